// Round 9
// baseline (704.774 us; speedup 1.0000x reference)
//
#include <hip/hip_runtime.h>
#include <hip/hip_bf16.h>
#include <math.h>

#define B_SZ 2
#define L_SZ 2048
#define DMODEL 1024
#define DINNER 2048
#define DSTATE 16
#define DTRANK 64
#define M_ROWS (B_SZ * L_SZ)   // 4096

#define CH 32
#define CLEN (L_SZ / CH)
#define CPB 64

#define KSPLIT 8
#define KC (DINNER / KSPLIT)   // 256

typedef short shortx8 __attribute__((ext_vector_type(8)));
typedef float floatx4 __attribute__((ext_vector_type(4)));
typedef float floatx16 __attribute__((ext_vector_type(16)));

__device__ __forceinline__ float softplusf(float x) {
    return fmaxf(x, 0.f) + log1pf(expf(-fabsf(x)));
}
__device__ __forceinline__ float siluf(float x) {
    return x * (1.f / (1.f + expf(-x)));
}

__device__ __forceinline__ void async_ld16(const void* g, void* l) {
    __builtin_amdgcn_global_load_lds(
        (__attribute__((address_space(1))) void*)(unsigned long long)g,
        (__attribute__((address_space(3))) void*)(unsigned int)(unsigned long long)l,
        16, 0, 0);
}

// ---------------------------------------------------------------------------
// bf16 MFMA GEMM using 32x32x16, 128xBN tile, BK=64.
// A staged via global_load_lds (XOR swizzle keyed on (row>>1)&3, R8-verified).
// B loaded DIRECTLY global->VGPR with one-iteration register prefetch: the
// loads issue right after the A-ready barrier and complete under the MFMA
// phase (L2 latency ~200cyc ~ MFMA phase). Halves LDS write traffic and
// removes B's LDS reads -- LDS pipe was the binding resource (R8 model).
// A,B are 2-segment split-bf16: row = [hi (KP) | lo (KP)], stride 2*KP.
// Segments: hi*hi + hi*lo + lo*hi.
// ---------------------------------------------------------------------------
template <int BN, int KP>
__global__ __launch_bounds__(256) void gemm_bf16_nt(
    const unsigned short* __restrict__ A,
    const unsigned short* __restrict__ Bm,
    float* __restrict__ C, int ldc)
{
    constexpr int TN32 = BN / 64;                 // 32-wide n-tiles per wave
    constexpr int NIT = KP / 64;                  // k0-iters per segment
    __shared__ unsigned short As[2 * 4096];       // [t][128 rows][32 k] = 16 KB

    const int tid = threadIdx.x;
    const int w = tid >> 6;
    const int lane = tid & 63;
    const int wm = w >> 1, wn = w & 1;
    const int m0 = blockIdx.y * 128;
    const int n0 = blockIdx.x * BN;

    const int r4 = lane >> 2;                        // staging row in 16-group
    const int csw = (lane & 3) ^ ((r4 >> 1) & 3);    // swizzled source chunk
    const int gk = csw * 8;                          // shorts offset
    const int l31 = lane & 31;
    const int khalf = lane >> 5;                     // 0/1: k-half within 16
    const int rsw = (l31 >> 1) & 3;                  // read-side swizzle key

    floatx16 acc[2][TN32] = {};
    shortx8 bcur[4 * TN32], bnxt[4 * TN32];

    // iteration -> (segment, k0). seg order: hi*hi, hi*lo, lo*hi
    auto issueA = [&](int it) {
        int seg = it / NIT;
        int k0 = (it - seg * NIT) * 64;
        const unsigned short* Aseg = A + (seg == 2 ? KP : 0);
#pragma unroll
        for (int t = 0; t < 2; ++t)
#pragma unroll
            for (int jj = 0; jj < 2; ++jj) {
                int j = w + jj * 4;
                async_ld16(Aseg + (size_t)(m0 + j * 16 + r4) * (2 * KP) + k0 + t * 32 + gk,
                           &As[t * 4096 + j * 512]);
            }
    };
    auto loadB = [&](shortx8* dst, int it) {
        int seg = it / NIT;
        int k0 = (it - seg * NIT) * 64;
        const unsigned short* Bseg = Bm + (seg == 1 ? KP : 0);
#pragma unroll
        for (int t = 0; t < 2; ++t)
#pragma unroll
            for (int kk = 0; kk < 2; ++kk)
#pragma unroll
                for (int j = 0; j < TN32; ++j)
                    dst[(t * 2 + kk) * TN32 + j] = *(const shortx8*)&Bseg[
                        (size_t)(n0 + wn * (BN / 2) + j * 32 + l31) * (2 * KP) +
                        k0 + t * 32 + kk * 16 + khalf * 8];
    };

    issueA(0);
    loadB(bcur, 0);

    const int it_total = 3 * NIT;
    for (int it = 0; it < it_total; ++it) {
        __syncthreads();                    // A(it) ready in LDS
        if (it + 1 < it_total) loadB(bnxt, it + 1);   // prefetch under MFMAs

#pragma unroll
        for (int t = 0; t < 2; ++t) {
#pragma unroll
            for (int kk = 0; kk < 2; ++kk) {
                const int pos = ((kk * 2 + khalf) ^ rsw) << 3;
                shortx8 af[2];
#pragma unroll
                for (int i = 0; i < 2; ++i) {
                    int row = wm * 64 + i * 32 + l31;
                    af[i] = *(const shortx8*)&As[t * 4096 + row * 32 + pos];
                }
#pragma unroll
                for (int i = 0; i < 2; ++i)
#pragma unroll
                    for (int j = 0; j < TN32; ++j)
                        acc[i][j] = __builtin_amdgcn_mfma_f32_32x32x16_bf16(
                            af[i], bcur[(t * 2 + kk) * TN32 + j], acc[i][j], 0, 0, 0);
            }
        }
        __syncthreads();                    // all waves done with As
        if (it + 1 < it_total) {
            issueA(it + 1);
#pragma unroll
            for (int z = 0; z < 4 * TN32; ++z) bcur[z] = bnxt[z];
        }
    }

    // epilogue: C/D layout col=lane&31, row=(reg&3)+8*(reg>>2)+4*(lane>>5) (m74/m101)
#pragma unroll
    for (int i = 0; i < 2; ++i) {
#pragma unroll
        for (int j = 0; j < TN32; ++j) {
            int col = n0 + wn * (BN / 2) + j * 32 + l31;
#pragma unroll
            for (int r = 0; r < 16; ++r) {
                int row = m0 + wm * 64 + i * 32 + (r & 3) + 8 * (r >> 2) + 4 * khalf;
                C[(size_t)row * ldc + col] = acc[i][j][r];
            }
        }
    }
}

// ---------------------------------------------------------------------------
// fp32 -> 2-segment split-bf16: row = [hi (K) | lo (K)], stride 2K
// ---------------------------------------------------------------------------
__global__ __launch_bounds__(256) void split2_kernel(
    const float* __restrict__ src, unsigned short* __restrict__ dst, int K)
{
    int i = blockIdx.x * 256 + threadIdx.x;
    int m = i / K;
    int k = i - m * K;
    float a = src[i];
    __hip_bfloat16 h = __float2bfloat16(a);
    __hip_bfloat16 l = __float2bfloat16(a - __bfloat162float(h));
    unsigned short* row = dst + (size_t)m * 2 * K;
    row[k] = *(unsigned short*)&h;
    row[K + k] = *(unsigned short*)&l;
}

// ---------------------------------------------------------------------------
// x_proj split-K partial GEMM + reduce
// ---------------------------------------------------------------------------
__global__ __launch_bounds__(256) void xproj_splitk(
    const float* __restrict__ u, const float* __restrict__ Wx,
    float* __restrict__ Cp)
{
    __shared__ float As[16][68];
    __shared__ float Bs[16][100];

    const int tid = threadIdx.x;
    const int ks = blockIdx.x;
    const int m0 = blockIdx.y * 64;
    const int tx = tid & 15;
    const int ty = tid >> 4;

    float acc[4][6] = {};

    const int arow = tid >> 2;
    const int akk = (tid & 3) * 4;

    for (int k0 = ks * KC; k0 < (ks + 1) * KC; k0 += 16) {
        {
            float4 v = *(const float4*)&u[(size_t)(m0 + arow) * DINNER + k0 + akk];
            As[akk + 0][arow] = v.x;
            As[akk + 1][arow] = v.y;
            As[akk + 2][arow] = v.z;
            As[akk + 3][arow] = v.w;
        }
        for (int idx = tid; idx < 384; idx += 256) {
            int row = idx >> 2;
            int kk = (idx & 3) * 4;
            float4 v = *(const float4*)&Wx[(size_t)row * DINNER + k0 + kk];
            Bs[kk + 0][row] = v.x;
            Bs[kk + 1][row] = v.y;
            Bs[kk + 2][row] = v.z;
            Bs[kk + 3][row] = v.w;
        }
        __syncthreads();

#pragma unroll
        for (int k = 0; k < 16; ++k) {
            float a[4], b[6];
#pragma unroll
            for (int i = 0; i < 4; ++i) a[i] = As[k][ty * 4 + i];
#pragma unroll
            for (int j = 0; j < 6; ++j) b[j] = Bs[k][tx * 6 + j];
#pragma unroll
            for (int i = 0; i < 4; ++i)
#pragma unroll
                for (int j = 0; j < 6; ++j) acc[i][j] = fmaf(a[i], b[j], acc[i][j]);
        }
        __syncthreads();
    }

    float* outp = Cp + ((size_t)ks * M_ROWS + m0) * 96;
#pragma unroll
    for (int i = 0; i < 4; ++i)
#pragma unroll
        for (int j = 0; j < 6; ++j)
            outp[(ty * 4 + i) * 96 + tx * 6 + j] = acc[i][j];
}

__global__ __launch_bounds__(256) void xproj_reduce(
    const float* __restrict__ Cp, float* __restrict__ xdbl)
{
    int i = blockIdx.x * 256 + threadIdx.x;
    float s = 0.f;
#pragma unroll
    for (int c = 0; c < KSPLIT; ++c)
        s += Cp[(size_t)c * M_ROWS * 96 + i];
    xdbl[i] = s;
}

// ---------------------------------------------------------------------------
// fp32 GEMM (dt_proj, K=64)
// ---------------------------------------------------------------------------
template <int BM, int BN, int BK, int TM, int TN, bool BOUND_N, int EPI>
__global__ __launch_bounds__(256) void gemm_nt(
    const float* __restrict__ A, int lda,
    const float* __restrict__ Bmat, int ldb,
    float* __restrict__ C, int ldc,
    int M, int N, int K, const float* __restrict__ bias)
{
    __shared__ float As[BK][BM + 4];
    __shared__ float Bs[BK][BN + 4];

    const int tid = threadIdx.x;
    const int tx = tid % (BN / TN);
    const int ty = tid / (BN / TN);
    const int m0 = blockIdx.y * BM;
    const int n0 = blockIdx.x * BN;

    float acc[TM][TN];
#pragma unroll
    for (int i = 0; i < TM; ++i)
#pragma unroll
        for (int j = 0; j < TN; ++j) acc[i][j] = 0.f;

    for (int k0 = 0; k0 < K; k0 += BK) {
        for (int idx = tid * 4; idx < BM * BK; idx += 256 * 4) {
            int row = idx / BK;
            int kk = idx % BK;
            float4 v = *(const float4*)&A[(size_t)(m0 + row) * lda + k0 + kk];
            As[kk + 0][row] = v.x;
            As[kk + 1][row] = v.y;
            As[kk + 2][row] = v.z;
            As[kk + 3][row] = v.w;
        }
        for (int idx = tid * 4; idx < BN * BK; idx += 256 * 4) {
            int row = idx / BK;
            int kk = idx % BK;
            float4 v;
            if (!BOUND_N || (n0 + row) < N)
                v = *(const float4*)&Bmat[(size_t)(n0 + row) * ldb + k0 + kk];
            else
                v = make_float4(0.f, 0.f, 0.f, 0.f);
            Bs[kk + 0][row] = v.x;
            Bs[kk + 1][row] = v.y;
            Bs[kk + 2][row] = v.z;
            Bs[kk + 3][row] = v.w;
        }
        __syncthreads();

#pragma unroll
        for (int k = 0; k < BK; ++k) {
            float a[TM], b[TN];
#pragma unroll
            for (int i = 0; i < TM; ++i) a[i] = As[k][ty * TM + i];
#pragma unroll
            for (int j = 0; j < TN; ++j) b[j] = Bs[k][tx * TN + j];
#pragma unroll
            for (int i = 0; i < TM; ++i)
#pragma unroll
                for (int j = 0; j < TN; ++j) acc[i][j] = fmaf(a[i], b[j], acc[i][j]);
        }
        __syncthreads();
    }

#pragma unroll
    for (int i = 0; i < TM; ++i) {
        int m = m0 + ty * TM + i;
#pragma unroll
        for (int j = 0; j < TN; ++j) {
            int n = n0 + tx * TN + j;
            if (BOUND_N && n >= N) continue;
            float v = acc[i][j];
            if (EPI == 1) v = softplusf(v + bias[n]);
            C[(size_t)m * ldc + n] = v;
        }
    }
}

// ---------------------------------------------------------------------------
// conv + silu, float4 over channels
// ---------------------------------------------------------------------------
__global__ __launch_bounds__(256) void conv_silu_v4(
    const float* __restrict__ xz, const float* __restrict__ cw,
    const float* __restrict__ cb, float* __restrict__ u)
{
    int i = blockIdx.x * 256 + threadIdx.x;      // over M_ROWS * 512
    int dq = (i & 511) << 2;
    int bl = i >> 9;
    int b = bl >> 11;
    int l = bl & 2047;

    float4 W0 = *(const float4*)&cw[(dq + 0) * 4];
    float4 W1 = *(const float4*)&cw[(dq + 1) * 4];
    float4 W2 = *(const float4*)&cw[(dq + 2) * 4];
    float4 W3 = *(const float4*)&cw[(dq + 3) * 4];
    float4 acc = *(const float4*)&cb[dq];

#pragma unroll
    for (int k = 0; k < 4; ++k) {
        int ls = l + k - 3;
        if (ls >= 0) {
            float4 v = *(const float4*)&xz[((size_t)(b << 11) + ls) * 4096 + dq];
            acc.x = fmaf(v.x, ((const float*)&W0)[k], acc.x);
            acc.y = fmaf(v.y, ((const float*)&W1)[k], acc.y);
            acc.z = fmaf(v.z, ((const float*)&W2)[k], acc.z);
            acc.w = fmaf(v.w, ((const float*)&W3)[k], acc.w);
        }
    }
    float4 r = make_float4(siluf(acc.x), siluf(acc.y), siluf(acc.z), siluf(acc.w));
    *(float4*)&u[(size_t)bl * DINNER + dq] = r;
}

// ---------------------------------------------------------------------------
// Chunked selective scan (3 passes). PASS3 fuses gate + split-bf16 y2
// (2-segment layout: row = [hi | lo], stride 2*DINNER).
// ---------------------------------------------------------------------------
template <bool PASS3>
__global__ __launch_bounds__(256) void scan_chunk(
    const float* __restrict__ dbuf, const float* __restrict__ ubuf,
    const float* __restrict__ xdbl, const float* __restrict__ A_log,
    const float* __restrict__ Dv,
    float* __restrict__ Pbuf, float* __restrict__ Sbuf,
    const float* __restrict__ xz, unsigned short* __restrict__ y2)
{
    __shared__ float sd[16][CPB];
    __shared__ float su[16][CPB];
    __shared__ float sB[16][DSTATE];
    __shared__ float sC[16][DSTATE];

    const int tid = threadIdx.x;
    const int c    = blockIdx.x % CH;
    const int dblk = (blockIdx.x / CH) % (DINNER / CPB);
    const int b    = blockIdx.x / (CH * (DINNER / CPB));
    const int d0 = dblk * CPB;
    const int dg = tid >> 2;
    const int q  = tid & 3;
    const int d  = d0 + dg;
    const size_t base_bl = (size_t)b * L_SZ + (size_t)c * CLEN;

    float Ac[4], h[4], p[4];
#pragma unroll
    for (int j = 0; j < 4; ++j) {
        Ac[j] = -expf(A_log[d * DSTATE + 4 * q + j]);
        p[j] = 1.f;
    }
    const size_t psoff = (((size_t)b * CH + c) * DINNER + d0) * DSTATE + (size_t)tid * 4;
    if (PASS3) {
        float4 h0 = *(const float4*)&Sbuf[psoff];
        h[0] = h0.x; h[1] = h0.y; h[2] = h0.z; h[3] = h0.w;
    } else {
        h[0] = h[1] = h[2] = h[3] = 0.f;
    }
    const float Dd = PASS3 ? Dv[d] : 0.f;

    const int ls = tid >> 4;
    const int g4 = (tid & 15) * 4;
    const int ln = tid & 15;

    float4 r_d = *(const float4*)&dbuf[(base_bl + ls) * DINNER + d0 + g4];
    float4 r_u = *(const float4*)&ubuf[(base_bl + ls) * DINNER + d0 + g4];
    float r_B = xdbl[(base_bl + ls) * 96 + 64 + ln];
    float r_C = xdbl[(base_bl + ls) * 96 + 80 + ln];

    for (int l0 = 0; l0 < CLEN; l0 += 16) {
        __syncthreads();
        *(float4*)&sd[ls][g4] = r_d;
        *(float4*)&su[ls][g4] = r_u;
        sB[ls][ln] = r_B;
        sC[ls][ln] = r_C;
        __syncthreads();

        if (l0 + 16 < CLEN) {
            r_d = *(const float4*)&dbuf[(base_bl + l0 + 16 + ls) * DINNER + d0 + g4];
            r_u = *(const float4*)&ubuf[(base_bl + l0 + 16 + ls) * DINNER + d0 + g4];
            r_B = xdbl[(base_bl + l0 + 16 + ls) * 96 + 64 + ln];
            r_C = xdbl[(base_bl + l0 + 16 + ls) * 96 + 80 + ln];
        }

#pragma unroll
        for (int s = 0; s < 16; ++s) {
            float dl = sd[s][dg];
            float ul = su[s][dg];
            float4 Bv = *(float4*)&sB[s][4 * q];
            float dbu = dl * ul;
            float dA0 = expf(dl * Ac[0]);
            float dA1 = expf(dl * Ac[1]);
            float dA2 = expf(dl * Ac[2]);
            float dA3 = expf(dl * Ac[3]);
            h[0] = fmaf(dA0, h[0], dbu * Bv.x);
            h[1] = fmaf(dA1, h[1], dbu * Bv.y);
            h[2] = fmaf(dA2, h[2], dbu * Bv.z);
            h[3] = fmaf(dA3, h[3], dbu * Bv.w);
            if (!PASS3) {
                p[0] *= dA0; p[1] *= dA1; p[2] *= dA2; p[3] *= dA3;
            } else {
                float4 Cv = *(float4*)&sC[s][4 * q];
                float y = h[0] * Cv.x + h[1] * Cv.y + h[2] * Cv.z + h[3] * Cv.w;
                y += __shfl_xor(y, 1);
                y += __shfl_xor(y, 2);
                if (q == 0) su[s][dg] = fmaf(ul, Dd, y);
            }
        }

        if (PASS3) {
            __syncthreads();
            // fused gate + split-bf16 (2-segment)
            size_t row = base_bl + l0 + ls;
            float4 yv = *(float4*)&su[ls][g4];
            float4 rv = *(const float4*)&xz[row * 4096 + 2048 + d0 + g4];
            float a0 = yv.x * siluf(rv.x);
            float a1 = yv.y * siluf(rv.y);
            float a2 = yv.z * siluf(rv.z);
            float a3 = yv.w * siluf(rv.w);
            __hip_bfloat16 h0 = __float2bfloat16(a0), h1 = __float2bfloat16(a1);
            __hip_bfloat16 h2 = __float2bfloat16(a2), h3 = __float2bfloat16(a3);
            __hip_bfloat16 l0b = __float2bfloat16(a0 - __bfloat162float(h0));
            __hip_bfloat16 l1b = __float2bfloat16(a1 - __bfloat162float(h1));
            __hip_bfloat16 l2b = __float2bfloat16(a2 - __bfloat162float(h2));
            __hip_bfloat16 l3b = __float2bfloat16(a3 - __bfloat162float(h3));
            ushort4 hv = make_ushort4(*(unsigned short*)&h0, *(unsigned short*)&h1,
                                      *(unsigned short*)&h2, *(unsigned short*)&h3);
            ushort4 lv = make_ushort4(*(unsigned short*)&l0b, *(unsigned short*)&l1b,
                                      *(unsigned short*)&l2b, *(unsigned short*)&l3b);
            unsigned short* yrow = y2 + row * 2 * DINNER + d0 + g4;
            *(ushort4*)&yrow[0] = hv;
            *(ushort4*)&yrow[DINNER] = lv;
        }
    }

    if (!PASS3) {
        *(float4*)&Pbuf[psoff] = make_float4(p[0], p[1], p[2], p[3]);
        *(float4*)&Sbuf[psoff] = make_float4(h[0], h[1], h[2], h[3]);
    }
}

__global__ __launch_bounds__(256) void scan_combine(
    const float* __restrict__ Pbuf, float* __restrict__ Sbuf)
{
    int t = blockIdx.x * 256 + threadIdx.x;
    int b = t >> 15;
    int rem = t & 32767;
    size_t base = (size_t)b * CH * DINNER * DSTATE + rem;
    float H = 0.f;
#pragma unroll 4
    for (int c = 0; c < CH; ++c) {
        size_t off = base + (size_t)c * DINNER * DSTATE;
        float S = Sbuf[off];
        float P = Pbuf[off];
        Sbuf[off] = H;
        H = fmaf(P, H, S);
    }
}

// ---------------------------------------------------------------------------
extern "C" void kernel_launch(void* const* d_in, const int* in_sizes, int n_in,
                              void* d_out, int out_size, void* d_ws, size_t ws_size,
                              hipStream_t stream)
{
    const float* x          = (const float*)d_in[0];
    const float* in_proj_w  = (const float*)d_in[1];
    const float* conv_w     = (const float*)d_in[2];
    const float* conv_b     = (const float*)d_in[3];
    const float* x_proj_w   = (const float*)d_in[4];
    const float* dt_proj_w  = (const float*)d_in[5];
    const float* dt_proj_b  = (const float*)d_in[6];
    const float* A_log      = (const float*)d_in[7];
    const float* Dv         = (const float*)d_in[8];
    const float* out_proj_w = (const float*)d_in[9];
    float* out = (float*)d_out;

    // workspace layout (bytes):
    char* w = (char*)d_ws;
    float* xz   = (float*)(w);                       // 64 MB
    float* u    = (float*)(w + 67108864);            // 32 MB
    float* dbuf = (float*)(w + 100663296);           // 32 MB
    float* xdbl = (float*)(w + 134217728);           // 1.5 MB
    float* Pbuf = (float*)(w + 135790592);           // 8 MB
    float* Sbuf = (float*)(w + 144179200);           // 8 MB (ends 152567808)
    unsigned short* x2  = (unsigned short*)(w + 152567808);  // 16 MB [4096][2048]
    unsigned short* w2a = (unsigned short*)(w + 169345024);  // 16 MB [4096][2048]
    unsigned short* y2  = x2;                                 // 32 MB [4096][4096] (stage 6+)
    unsigned short* w2b = (unsigned short*)(w + 135790592);   // 8 MB [1024][4096] over Pbuf (dead)
    float* Cp = (float*)(w + 152567808);             // xproj partials (x2 region, dead at 4)

    // 1) split x and in_proj_w to 2-segment bf16
    split2_kernel<<<(M_ROWS * DMODEL) / 256, 256, 0, stream>>>(x, x2, DMODEL);
    split2_kernel<<<(2 * DINNER * DMODEL) / 256, 256, 0, stream>>>(in_proj_w, w2a, DMODEL);
    // 2) in_proj via 32x32x16 MFMA (A via LDS, B direct w/ register prefetch)
    {
        dim3 g(4096 / 128, M_ROWS / 128);
        gemm_bf16_nt<128, 1024><<<g, 256, 0, stream>>>(x2, w2a, xz, 4096);
    }
    // 3) conv + silu -> u
    conv_silu_v4<<<(M_ROWS * 512) / 256, 256, 0, stream>>>(xz, conv_w, conv_b, u);
    // 4) x_proj via split-K
    {
        dim3 g(KSPLIT, M_ROWS / 64);
        xproj_splitk<<<g, 256, 0, stream>>>(u, x_proj_w, Cp);
        xproj_reduce<<<(M_ROWS * 96) / 256, 256, 0, stream>>>(Cp, xdbl);
    }
    // 5) dt_proj + softplus -> dbuf (fp32, K=64)
    {
        dim3 g(2048 / 128, M_ROWS / 128);
        gemm_nt<128, 128, 16, 8, 8, false, 1><<<g, 256, 0, stream>>>(
            xdbl, 96, dt_proj_w, 64, dbuf, 2048, M_ROWS, 2048, 64, dt_proj_b);
    }
    // 6) chunked selective scan; pass3 fuses gate + split into y2
    {
        const int nblk = B_SZ * (DINNER / CPB) * CH;
        scan_chunk<false><<<nblk, 256, 0, stream>>>(dbuf, u, xdbl, A_log, Dv, Pbuf, Sbuf, nullptr, nullptr);
        scan_combine<<<B_SZ * DINNER * DSTATE / 256, 256, 0, stream>>>(Pbuf, Sbuf);
        scan_chunk<true><<<nblk, 256, 0, stream>>>(dbuf, u, xdbl, A_log, Dv, nullptr, Sbuf, xz, y2);
    }
    // 7) split out_proj_w
    split2_kernel<<<(DMODEL * DINNER) / 256, 256, 0, stream>>>(out_proj_w, w2b, DINNER);
    // 8) out_proj via 32x32x16 MFMA
    {
        dim3 g(1024 / 64, M_ROWS / 128);
        gemm_bf16_nt<64, 2048><<<g, 256, 0, stream>>>(y2, w2b, out, 1024);
    }
}

// Round 10
// 571.844 us; speedup vs baseline: 1.2325x; 1.2325x over previous
//
#include <hip/hip_runtime.h>
#include <hip/hip_bf16.h>
#include <math.h>

#define B_SZ 2
#define L_SZ 2048
#define DMODEL 1024
#define DINNER 2048
#define DSTATE 16
#define DTRANK 64
#define M_ROWS (B_SZ * L_SZ)   // 4096

#define CH 32
#define CLEN (L_SZ / CH)
#define CPB 64

#define KSPLIT 8
#define KC (DINNER / KSPLIT)   // 256

typedef short shortx8 __attribute__((ext_vector_type(8)));
typedef float floatx4 __attribute__((ext_vector_type(4)));
typedef float floatx16 __attribute__((ext_vector_type(16)));

__device__ __forceinline__ float softplusf(float x) {
    return fmaxf(x, 0.f) + log1pf(expf(-fabsf(x)));
}
__device__ __forceinline__ float siluf(float x) {
    return x * (1.f / (1.f + expf(-x)));
}

__device__ __forceinline__ void async_ld16(const void* g, void* l) {
    __builtin_amdgcn_global_load_lds(
        (__attribute__((address_space(1))) void*)(unsigned long long)g,
        (__attribute__((address_space(3))) void*)(unsigned int)(unsigned long long)l,
        16, 0, 0);
}

// ---------------------------------------------------------------------------
// bf16 MFMA GEMM using 32x32x16, 128xBN tile, BK=64 (R8 structure — best).
// Both A and B staged via global_load_lds; XOR bank swizzle keyed on
// (row>>1)&3 (LDS row base advances 16 banks/row; chunk^((row>>1)&3) spreads
// the four 16B positions so every bank-quad is hit exactly 4x = minimal).
// NOTE (R9 lesson): do NOT load B fragments direct global->VGPR — per-lane
// 16B at 4KB stride = 32 cache lines per instruction, VMEM-serialized.
// A,B are 2-segment split-bf16: row = [hi (KP) | lo (KP)], stride 2*KP.
// Segments: hi*hi + hi*lo + lo*hi (fp32 emulation, ~17-bit mantissa).
// ---------------------------------------------------------------------------
template <int BN, int KP>
__global__ __launch_bounds__(256) void gemm_bf16_nt(
    const unsigned short* __restrict__ A,
    const unsigned short* __restrict__ Bm,
    float* __restrict__ C, int ldc)
{
    constexpr int TN32 = BN / 64;                 // 32-wide n-tiles per wave
    __shared__ unsigned short As[2 * 4096];       // [t][128 rows][32 k]
    __shared__ unsigned short Bs[2 * BN * 32];

    const int tid = threadIdx.x;
    const int w = tid >> 6;
    const int lane = tid & 63;
    const int wm = w >> 1, wn = w & 1;
    const int m0 = blockIdx.y * 128;
    const int n0 = blockIdx.x * BN;

    const int r4 = lane >> 2;                        // staging row in 16-group
    const int csw = (lane & 3) ^ ((r4 >> 1) & 3);    // swizzled source chunk
    const int gk = csw * 8;                          // shorts offset
    const int l31 = lane & 31;
    const int khalf = lane >> 5;                     // 0/1: k-half within 16
    const int rsw = (l31 >> 1) & 3;                  // read-side swizzle key

    floatx16 acc[2][TN32] = {};

#pragma unroll
    for (int seg = 0; seg < 3; ++seg) {
        const unsigned short* Aseg = A + (seg == 2 ? KP : 0);
        const unsigned short* Bseg = Bm + (seg == 1 ? KP : 0);
        for (int k0 = 0; k0 < KP; k0 += 64) {
#pragma unroll
            for (int t = 0; t < 2; ++t) {
#pragma unroll
                for (int jj = 0; jj < 2; ++jj) {
                    int j = w + jj * 4;
                    async_ld16(Aseg + (size_t)(m0 + j * 16 + r4) * (2 * KP) + k0 + t * 32 + gk,
                               &As[t * 4096 + j * 512]);
                }
#pragma unroll
                for (int jj = 0; jj < BN / 64; ++jj) {
                    int j = w + jj * 4;
                    async_ld16(Bseg + (size_t)(n0 + j * 16 + r4) * (2 * KP) + k0 + t * 32 + gk,
                               &Bs[t * BN * 32 + j * 512]);
                }
            }
            __syncthreads();

#pragma unroll
            for (int t = 0; t < 2; ++t) {
#pragma unroll
                for (int kk = 0; kk < 2; ++kk) {
                    const int pos = ((kk * 2 + khalf) ^ rsw) << 3;
                    shortx8 af[2], bf[TN32];
#pragma unroll
                    for (int i = 0; i < 2; ++i) {
                        int row = wm * 64 + i * 32 + l31;
                        af[i] = *(const shortx8*)&As[t * 4096 + row * 32 + pos];
                    }
#pragma unroll
                    for (int j = 0; j < TN32; ++j) {
                        int col = wn * (BN / 2) + j * 32 + l31;
                        bf[j] = *(const shortx8*)&Bs[t * BN * 32 + col * 32 + pos];
                    }
#pragma unroll
                    for (int i = 0; i < 2; ++i)
#pragma unroll
                        for (int j = 0; j < TN32; ++j)
                            acc[i][j] = __builtin_amdgcn_mfma_f32_32x32x16_bf16(
                                af[i], bf[j], acc[i][j], 0, 0, 0);
                }
            }
            __syncthreads();
        }
    }

    // epilogue: C/D layout col=lane&31, row=(reg&3)+8*(reg>>2)+4*(lane>>5) (m74/m101)
#pragma unroll
    for (int i = 0; i < 2; ++i) {
#pragma unroll
        for (int j = 0; j < TN32; ++j) {
            int col = n0 + wn * (BN / 2) + j * 32 + l31;
#pragma unroll
            for (int r = 0; r < 16; ++r) {
                int row = m0 + wm * 64 + i * 32 + (r & 3) + 8 * (r >> 2) + 4 * khalf;
                C[(size_t)row * ldc + col] = acc[i][j][r];
            }
        }
    }
}

// ---------------------------------------------------------------------------
// fp32 -> 2-segment split-bf16: row = [hi (K) | lo (K)], stride 2K
// ---------------------------------------------------------------------------
__global__ __launch_bounds__(256) void split2_kernel(
    const float* __restrict__ src, unsigned short* __restrict__ dst, int K)
{
    int i = blockIdx.x * 256 + threadIdx.x;
    int m = i / K;
    int k = i - m * K;
    float a = src[i];
    __hip_bfloat16 h = __float2bfloat16(a);
    __hip_bfloat16 l = __float2bfloat16(a - __bfloat162float(h));
    unsigned short* row = dst + (size_t)m * 2 * K;
    row[k] = *(unsigned short*)&h;
    row[K + k] = *(unsigned short*)&l;
}

// ---------------------------------------------------------------------------
// x_proj split-K partial GEMM + reduce
// ---------------------------------------------------------------------------
__global__ __launch_bounds__(256) void xproj_splitk(
    const float* __restrict__ u, const float* __restrict__ Wx,
    float* __restrict__ Cp)
{
    __shared__ float As[16][68];
    __shared__ float Bs[16][100];

    const int tid = threadIdx.x;
    const int ks = blockIdx.x;
    const int m0 = blockIdx.y * 64;
    const int tx = tid & 15;
    const int ty = tid >> 4;

    float acc[4][6] = {};

    const int arow = tid >> 2;
    const int akk = (tid & 3) * 4;

    for (int k0 = ks * KC; k0 < (ks + 1) * KC; k0 += 16) {
        {
            float4 v = *(const float4*)&u[(size_t)(m0 + arow) * DINNER + k0 + akk];
            As[akk + 0][arow] = v.x;
            As[akk + 1][arow] = v.y;
            As[akk + 2][arow] = v.z;
            As[akk + 3][arow] = v.w;
        }
        for (int idx = tid; idx < 384; idx += 256) {
            int row = idx >> 2;
            int kk = (idx & 3) * 4;
            float4 v = *(const float4*)&Wx[(size_t)row * DINNER + k0 + kk];
            Bs[kk + 0][row] = v.x;
            Bs[kk + 1][row] = v.y;
            Bs[kk + 2][row] = v.z;
            Bs[kk + 3][row] = v.w;
        }
        __syncthreads();

#pragma unroll
        for (int k = 0; k < 16; ++k) {
            float a[4], b[6];
#pragma unroll
            for (int i = 0; i < 4; ++i) a[i] = As[k][ty * 4 + i];
#pragma unroll
            for (int j = 0; j < 6; ++j) b[j] = Bs[k][tx * 6 + j];
#pragma unroll
            for (int i = 0; i < 4; ++i)
#pragma unroll
                for (int j = 0; j < 6; ++j) acc[i][j] = fmaf(a[i], b[j], acc[i][j]);
        }
        __syncthreads();
    }

    float* outp = Cp + ((size_t)ks * M_ROWS + m0) * 96;
#pragma unroll
    for (int i = 0; i < 4; ++i)
#pragma unroll
        for (int j = 0; j < 6; ++j)
            outp[(ty * 4 + i) * 96 + tx * 6 + j] = acc[i][j];
}

__global__ __launch_bounds__(256) void xproj_reduce(
    const float* __restrict__ Cp, float* __restrict__ xdbl)
{
    int i = blockIdx.x * 256 + threadIdx.x;
    float s = 0.f;
#pragma unroll
    for (int c = 0; c < KSPLIT; ++c)
        s += Cp[(size_t)c * M_ROWS * 96 + i];
    xdbl[i] = s;
}

// ---------------------------------------------------------------------------
// fp32 GEMM (dt_proj, K=64)
// ---------------------------------------------------------------------------
template <int BM, int BN, int BK, int TM, int TN, bool BOUND_N, int EPI>
__global__ __launch_bounds__(256) void gemm_nt(
    const float* __restrict__ A, int lda,
    const float* __restrict__ Bmat, int ldb,
    float* __restrict__ C, int ldc,
    int M, int N, int K, const float* __restrict__ bias)
{
    __shared__ float As[BK][BM + 4];
    __shared__ float Bs[BK][BN + 4];

    const int tid = threadIdx.x;
    const int tx = tid % (BN / TN);
    const int ty = tid / (BN / TN);
    const int m0 = blockIdx.y * BM;
    const int n0 = blockIdx.x * BN;

    float acc[TM][TN];
#pragma unroll
    for (int i = 0; i < TM; ++i)
#pragma unroll
        for (int j = 0; j < TN; ++j) acc[i][j] = 0.f;

    for (int k0 = 0; k0 < K; k0 += BK) {
        for (int idx = tid * 4; idx < BM * BK; idx += 256 * 4) {
            int row = idx / BK;
            int kk = idx % BK;
            float4 v = *(const float4*)&A[(size_t)(m0 + row) * lda + k0 + kk];
            As[kk + 0][row] = v.x;
            As[kk + 1][row] = v.y;
            As[kk + 2][row] = v.z;
            As[kk + 3][row] = v.w;
        }
        for (int idx = tid * 4; idx < BN * BK; idx += 256 * 4) {
            int row = idx / BK;
            int kk = idx % BK;
            float4 v;
            if (!BOUND_N || (n0 + row) < N)
                v = *(const float4*)&Bmat[(size_t)(n0 + row) * ldb + k0 + kk];
            else
                v = make_float4(0.f, 0.f, 0.f, 0.f);
            Bs[kk + 0][row] = v.x;
            Bs[kk + 1][row] = v.y;
            Bs[kk + 2][row] = v.z;
            Bs[kk + 3][row] = v.w;
        }
        __syncthreads();

#pragma unroll
        for (int k = 0; k < BK; ++k) {
            float a[TM], b[TN];
#pragma unroll
            for (int i = 0; i < TM; ++i) a[i] = As[k][ty * TM + i];
#pragma unroll
            for (int j = 0; j < TN; ++j) b[j] = Bs[k][tx * TN + j];
#pragma unroll
            for (int i = 0; i < TM; ++i)
#pragma unroll
                for (int j = 0; j < TN; ++j) acc[i][j] = fmaf(a[i], b[j], acc[i][j]);
        }
        __syncthreads();
    }

#pragma unroll
    for (int i = 0; i < TM; ++i) {
        int m = m0 + ty * TM + i;
#pragma unroll
        for (int j = 0; j < TN; ++j) {
            int n = n0 + tx * TN + j;
            if (BOUND_N && n >= N) continue;
            float v = acc[i][j];
            if (EPI == 1) v = softplusf(v + bias[n]);
            C[(size_t)m * ldc + n] = v;
        }
    }
}

// ---------------------------------------------------------------------------
// conv + silu, float4 over channels
// ---------------------------------------------------------------------------
__global__ __launch_bounds__(256) void conv_silu_v4(
    const float* __restrict__ xz, const float* __restrict__ cw,
    const float* __restrict__ cb, float* __restrict__ u)
{
    int i = blockIdx.x * 256 + threadIdx.x;      // over M_ROWS * 512
    int dq = (i & 511) << 2;
    int bl = i >> 9;
    int b = bl >> 11;
    int l = bl & 2047;

    float4 W0 = *(const float4*)&cw[(dq + 0) * 4];
    float4 W1 = *(const float4*)&cw[(dq + 1) * 4];
    float4 W2 = *(const float4*)&cw[(dq + 2) * 4];
    float4 W3 = *(const float4*)&cw[(dq + 3) * 4];
    float4 acc = *(const float4*)&cb[dq];

#pragma unroll
    for (int k = 0; k < 4; ++k) {
        int ls = l + k - 3;
        if (ls >= 0) {
            float4 v = *(const float4*)&xz[((size_t)(b << 11) + ls) * 4096 + dq];
            acc.x = fmaf(v.x, ((const float*)&W0)[k], acc.x);
            acc.y = fmaf(v.y, ((const float*)&W1)[k], acc.y);
            acc.z = fmaf(v.z, ((const float*)&W2)[k], acc.z);
            acc.w = fmaf(v.w, ((const float*)&W3)[k], acc.w);
        }
    }
    float4 r = make_float4(siluf(acc.x), siluf(acc.y), siluf(acc.z), siluf(acc.w));
    *(float4*)&u[(size_t)bl * DINNER + dq] = r;
}

// ---------------------------------------------------------------------------
// Chunked selective scan (3 passes). PASS3 fuses gate + split-bf16 y2
// (2-segment layout: row = [hi | lo], stride 2*DINNER).
// Pass1 computes P = exp(Ac * sum(delta)) (identity: prod exp = exp of sum)
// -> 1 add/step instead of 4 mul/step.
// ---------------------------------------------------------------------------
template <bool PASS3>
__global__ __launch_bounds__(256) void scan_chunk(
    const float* __restrict__ dbuf, const float* __restrict__ ubuf,
    const float* __restrict__ xdbl, const float* __restrict__ A_log,
    const float* __restrict__ Dv,
    float* __restrict__ Pbuf, float* __restrict__ Sbuf,
    const float* __restrict__ xz, unsigned short* __restrict__ y2)
{
    __shared__ float sd[16][CPB];
    __shared__ float su[16][CPB];
    __shared__ float sB[16][DSTATE];
    __shared__ float sC[16][DSTATE];

    const int tid = threadIdx.x;
    const int c    = blockIdx.x % CH;
    const int dblk = (blockIdx.x / CH) % (DINNER / CPB);
    const int b    = blockIdx.x / (CH * (DINNER / CPB));
    const int d0 = dblk * CPB;
    const int dg = tid >> 2;
    const int q  = tid & 3;
    const int d  = d0 + dg;
    const size_t base_bl = (size_t)b * L_SZ + (size_t)c * CLEN;

    float Ac[4], h[4];
    float sdl = 0.f;                       // sum of delta over chunk (pass1)
#pragma unroll
    for (int j = 0; j < 4; ++j)
        Ac[j] = -expf(A_log[d * DSTATE + 4 * q + j]);
    const size_t psoff = (((size_t)b * CH + c) * DINNER + d0) * DSTATE + (size_t)tid * 4;
    if (PASS3) {
        float4 h0 = *(const float4*)&Sbuf[psoff];
        h[0] = h0.x; h[1] = h0.y; h[2] = h0.z; h[3] = h0.w;
    } else {
        h[0] = h[1] = h[2] = h[3] = 0.f;
    }
    const float Dd = PASS3 ? Dv[d] : 0.f;

    const int ls = tid >> 4;
    const int g4 = (tid & 15) * 4;
    const int ln = tid & 15;

    float4 r_d = *(const float4*)&dbuf[(base_bl + ls) * DINNER + d0 + g4];
    float4 r_u = *(const float4*)&ubuf[(base_bl + ls) * DINNER + d0 + g4];
    float r_B = xdbl[(base_bl + ls) * 96 + 64 + ln];
    float r_C = xdbl[(base_bl + ls) * 96 + 80 + ln];

    for (int l0 = 0; l0 < CLEN; l0 += 16) {
        __syncthreads();
        *(float4*)&sd[ls][g4] = r_d;
        *(float4*)&su[ls][g4] = r_u;
        sB[ls][ln] = r_B;
        sC[ls][ln] = r_C;
        __syncthreads();

        if (l0 + 16 < CLEN) {
            r_d = *(const float4*)&dbuf[(base_bl + l0 + 16 + ls) * DINNER + d0 + g4];
            r_u = *(const float4*)&ubuf[(base_bl + l0 + 16 + ls) * DINNER + d0 + g4];
            r_B = xdbl[(base_bl + l0 + 16 + ls) * 96 + 64 + ln];
            r_C = xdbl[(base_bl + l0 + 16 + ls) * 96 + 80 + ln];
        }

#pragma unroll
        for (int s = 0; s < 16; ++s) {
            float dl = sd[s][dg];
            float ul = su[s][dg];
            float4 Bv = *(float4*)&sB[s][4 * q];
            float dbu = dl * ul;
            float dA0 = expf(dl * Ac[0]);
            float dA1 = expf(dl * Ac[1]);
            float dA2 = expf(dl * Ac[2]);
            float dA3 = expf(dl * Ac[3]);
            h[0] = fmaf(dA0, h[0], dbu * Bv.x);
            h[1] = fmaf(dA1, h[1], dbu * Bv.y);
            h[2] = fmaf(dA2, h[2], dbu * Bv.z);
            h[3] = fmaf(dA3, h[3], dbu * Bv.w);
            if (!PASS3) {
                sdl += dl;
            } else {
                float4 Cv = *(float4*)&sC[s][4 * q];
                float y = h[0] * Cv.x + h[1] * Cv.y + h[2] * Cv.z + h[3] * Cv.w;
                y += __shfl_xor(y, 1);
                y += __shfl_xor(y, 2);
                if (q == 0) su[s][dg] = fmaf(ul, Dd, y);
            }
        }

        if (PASS3) {
            __syncthreads();
            // fused gate + split-bf16 (2-segment)
            size_t row = base_bl + l0 + ls;
            float4 yv = *(float4*)&su[ls][g4];
            float4 rv = *(const float4*)&xz[row * 4096 + 2048 + d0 + g4];
            float a0 = yv.x * siluf(rv.x);
            float a1 = yv.y * siluf(rv.y);
            float a2 = yv.z * siluf(rv.z);
            float a3 = yv.w * siluf(rv.w);
            __hip_bfloat16 h0 = __float2bfloat16(a0), h1 = __float2bfloat16(a1);
            __hip_bfloat16 h2 = __float2bfloat16(a2), h3 = __float2bfloat16(a3);
            __hip_bfloat16 l0b = __float2bfloat16(a0 - __bfloat162float(h0));
            __hip_bfloat16 l1b = __float2bfloat16(a1 - __bfloat162float(h1));
            __hip_bfloat16 l2b = __float2bfloat16(a2 - __bfloat162float(h2));
            __hip_bfloat16 l3b = __float2bfloat16(a3 - __bfloat162float(h3));
            ushort4 hv = make_ushort4(*(unsigned short*)&h0, *(unsigned short*)&h1,
                                      *(unsigned short*)&h2, *(unsigned short*)&h3);
            ushort4 lv = make_ushort4(*(unsigned short*)&l0b, *(unsigned short*)&l1b,
                                      *(unsigned short*)&l2b, *(unsigned short*)&l3b);
            unsigned short* yrow = y2 + row * 2 * DINNER + d0 + g4;
            *(ushort4*)&yrow[0] = hv;
            *(ushort4*)&yrow[DINNER] = lv;
        }
    }

    if (!PASS3) {
        *(float4*)&Pbuf[psoff] = make_float4(expf(Ac[0] * sdl), expf(Ac[1] * sdl),
                                             expf(Ac[2] * sdl), expf(Ac[3] * sdl));
        *(float4*)&Sbuf[psoff] = make_float4(h[0], h[1], h[2], h[3]);
    }
}

__global__ __launch_bounds__(256) void scan_combine(
    const float* __restrict__ Pbuf, float* __restrict__ Sbuf)
{
    int t = blockIdx.x * 256 + threadIdx.x;
    int b = t >> 15;
    int rem = t & 32767;
    size_t base = (size_t)b * CH * DINNER * DSTATE + rem;
    float H = 0.f;
#pragma unroll 4
    for (int c = 0; c < CH; ++c) {
        size_t off = base + (size_t)c * DINNER * DSTATE;
        float S = Sbuf[off];
        float P = Pbuf[off];
        Sbuf[off] = H;
        H = fmaf(P, H, S);
    }
}

// ---------------------------------------------------------------------------
extern "C" void kernel_launch(void* const* d_in, const int* in_sizes, int n_in,
                              void* d_out, int out_size, void* d_ws, size_t ws_size,
                              hipStream_t stream)
{
    const float* x          = (const float*)d_in[0];
    const float* in_proj_w  = (const float*)d_in[1];
    const float* conv_w     = (const float*)d_in[2];
    const float* conv_b     = (const float*)d_in[3];
    const float* x_proj_w   = (const float*)d_in[4];
    const float* dt_proj_w  = (const float*)d_in[5];
    const float* dt_proj_b  = (const float*)d_in[6];
    const float* A_log      = (const float*)d_in[7];
    const float* Dv         = (const float*)d_in[8];
    const float* out_proj_w = (const float*)d_in[9];
    float* out = (float*)d_out;

    // workspace layout (bytes):
    char* w = (char*)d_ws;
    float* xz   = (float*)(w);                       // 64 MB
    float* u    = (float*)(w + 67108864);            // 32 MB
    float* dbuf = (float*)(w + 100663296);           // 32 MB
    float* xdbl = (float*)(w + 134217728);           // 1.5 MB
    float* Pbuf = (float*)(w + 135790592);           // 8 MB
    float* Sbuf = (float*)(w + 144179200);           // 8 MB (ends 152567808)
    unsigned short* x2  = (unsigned short*)(w + 152567808);  // 16 MB [4096][2048]
    unsigned short* w2a = (unsigned short*)(w + 169345024);  // 16 MB [4096][2048]
    unsigned short* y2  = x2;                                 // 32 MB [4096][4096] (stage 6+)
    unsigned short* w2b = (unsigned short*)(w + 135790592);   // 8 MB [1024][4096] over Pbuf (dead)
    float* Cp = (float*)(w + 152567808);             // xproj partials (x2 region, dead at 4)

    // 1) split x and in_proj_w to 2-segment bf16
    split2_kernel<<<(M_ROWS * DMODEL) / 256, 256, 0, stream>>>(x, x2, DMODEL);
    split2_kernel<<<(2 * DINNER * DMODEL) / 256, 256, 0, stream>>>(in_proj_w, w2a, DMODEL);
    // 2) in_proj via 32x32x16 MFMA (R8 structure)
    {
        dim3 g(4096 / 128, M_ROWS / 128);
        gemm_bf16_nt<128, 1024><<<g, 256, 0, stream>>>(x2, w2a, xz, 4096);
    }
    // 3) conv + silu -> u
    conv_silu_v4<<<(M_ROWS * 512) / 256, 256, 0, stream>>>(xz, conv_w, conv_b, u);
    // 4) x_proj via split-K
    {
        dim3 g(KSPLIT, M_ROWS / 64);
        xproj_splitk<<<g, 256, 0, stream>>>(u, x_proj_w, Cp);
        xproj_reduce<<<(M_ROWS * 96) / 256, 256, 0, stream>>>(Cp, xdbl);
    }
    // 5) dt_proj + softplus -> dbuf (fp32, K=64)
    {
        dim3 g(2048 / 128, M_ROWS / 128);
        gemm_nt<128, 128, 16, 8, 8, false, 1><<<g, 256, 0, stream>>>(
            xdbl, 96, dt_proj_w, 64, dbuf, 2048, M_ROWS, 2048, 64, dt_proj_b);
    }
    // 6) chunked selective scan; pass3 fuses gate + split into y2
    {
        const int nblk = B_SZ * (DINNER / CPB) * CH;
        scan_chunk<false><<<nblk, 256, 0, stream>>>(dbuf, u, xdbl, A_log, Dv, Pbuf, Sbuf, nullptr, nullptr);
        scan_combine<<<B_SZ * DINNER * DSTATE / 256, 256, 0, stream>>>(Pbuf, Sbuf);
        scan_chunk<true><<<nblk, 256, 0, stream>>>(dbuf, u, xdbl, A_log, Dv, nullptr, Sbuf, xz, y2);
    }
    // 7) split out_proj_w
    split2_kernel<<<(DMODEL * DINNER) / 256, 256, 0, stream>>>(out_proj_w, w2b, DINNER);
    // 8) out_proj via 32x32x16 MFMA
    {
        dim3 g(1024 / 64, M_ROWS / 128);
        gemm_bf16_nt<64, 2048><<<g, 256, 0, stream>>>(y2, w2b, out, 1024);
    }
}

// Round 11
// 518.820 us; speedup vs baseline: 1.3584x; 1.1022x over previous
//
#include <hip/hip_runtime.h>
#include <hip/hip_bf16.h>
#include <math.h>

#define B_SZ 2
#define L_SZ 2048
#define DMODEL 1024
#define DINNER 2048
#define DSTATE 16
#define DTRANK 64
#define M_ROWS (B_SZ * L_SZ)   // 4096

#define CH 32
#define CLEN (L_SZ / CH)
#define CPB 64

#define KSPLIT 8
#define KC (DINNER / KSPLIT)   // 256

typedef short shortx8 __attribute__((ext_vector_type(8)));
typedef float floatx4 __attribute__((ext_vector_type(4)));
typedef float floatx16 __attribute__((ext_vector_type(16)));

__device__ __forceinline__ float softplusf(float x) {
    return fmaxf(x, 0.f) + log1pf(expf(-fabsf(x)));
}
__device__ __forceinline__ float siluf(float x) {
    return x * (1.f / (1.f + expf(-x)));
}

__device__ __forceinline__ void async_ld16(const void* g, void* l) {
    __builtin_amdgcn_global_load_lds(
        (__attribute__((address_space(1))) void*)(unsigned long long)g,
        (__attribute__((address_space(3))) void*)(unsigned int)(unsigned long long)l,
        16, 0, 0);
}

// ---------------------------------------------------------------------------
// bf16 MFMA GEMM, 32x32x16, 128xBN tile, BK=64, SINGLE-PASS SEGMENT FUSION:
// per k0 stage A-hi, A-lo, B-hi, B-lo together (all three split-fp32 terms
// accumulate into the same acc), then issue ah*bh + ah*bl + al*bh from one
// LDS residency. vs R8's 3-segment loop: LDS writes x0.67, reads x0.67,
// barrier pairs x0.33 -- LDS pipe is the binding resource (R8 model).
// XOR bank swizzle keyed on (row>>1)&3 (R8-verified minimal conflicts).
// R9 lesson: never load B fragments direct global->VGPR (4KB-stride scatter).
// A,B 2-segment split-bf16: row = [hi (KP) | lo (KP)], stride 2*KP.
// ---------------------------------------------------------------------------
template <int BN, int KP>
__global__ __launch_bounds__(256) void gemm_bf16_nt(
    const unsigned short* __restrict__ A,
    const unsigned short* __restrict__ Bm,
    float* __restrict__ C, int ldc)
{
    constexpr int TN32 = BN / 64;                 // 32-wide n-tiles per wave
    __shared__ unsigned short As[2 * 8192];       // [seg][t][128 rows][32 k]
    __shared__ unsigned short Bs[2 * BN * 64];    // [seg][t][BN rows][32 k]

    const int tid = threadIdx.x;
    const int w = tid >> 6;
    const int lane = tid & 63;
    const int wm = w >> 1, wn = w & 1;
    const int m0 = blockIdx.y * 128;
    const int n0 = blockIdx.x * BN;

    const int r4 = lane >> 2;                        // staging row in 16-group
    const int csw = (lane & 3) ^ ((r4 >> 1) & 3);    // swizzled source chunk
    const int gk = csw * 8;                          // shorts offset
    const int l31 = lane & 31;
    const int khalf = lane >> 5;                     // 0/1: k-half within 16
    const int rsw = (l31 >> 1) & 3;                  // read-side swizzle key

    floatx16 acc[2][TN32] = {};

    for (int k0 = 0; k0 < KP; k0 += 64) {
#pragma unroll
        for (int seg = 0; seg < 2; ++seg) {
            const unsigned short* Asrc = A + seg * KP;
            const unsigned short* Bsrc = Bm + seg * KP;
#pragma unroll
            for (int t = 0; t < 2; ++t) {
#pragma unroll
                for (int jj = 0; jj < 2; ++jj) {
                    int j = w + jj * 4;
                    async_ld16(Asrc + (size_t)(m0 + j * 16 + r4) * (2 * KP) + k0 + t * 32 + gk,
                               &As[seg * 8192 + t * 4096 + j * 512]);
                }
#pragma unroll
                for (int jj = 0; jj < BN / 64; ++jj) {
                    int j = w + jj * 4;
                    async_ld16(Bsrc + (size_t)(n0 + j * 16 + r4) * (2 * KP) + k0 + t * 32 + gk,
                               &Bs[seg * BN * 64 + t * BN * 32 + j * 512]);
                }
            }
        }
        __syncthreads();

#pragma unroll
        for (int t = 0; t < 2; ++t) {
#pragma unroll
            for (int kk = 0; kk < 2; ++kk) {
                const int pos = ((kk * 2 + khalf) ^ rsw) << 3;
                shortx8 ah[2], al[2], bh[TN32], bl[TN32];
#pragma unroll
                for (int i = 0; i < 2; ++i) {
                    int row = wm * 64 + i * 32 + l31;
                    ah[i] = *(const shortx8*)&As[t * 4096 + row * 32 + pos];
                    al[i] = *(const shortx8*)&As[8192 + t * 4096 + row * 32 + pos];
                }
#pragma unroll
                for (int j = 0; j < TN32; ++j) {
                    int col = wn * (BN / 2) + j * 32 + l31;
                    bh[j] = *(const shortx8*)&Bs[t * BN * 32 + col * 32 + pos];
                    bl[j] = *(const shortx8*)&Bs[BN * 64 + t * BN * 32 + col * 32 + pos];
                }
#pragma unroll
                for (int i = 0; i < 2; ++i)
#pragma unroll
                    for (int j = 0; j < TN32; ++j) {
                        acc[i][j] = __builtin_amdgcn_mfma_f32_32x32x16_bf16(ah[i], bh[j], acc[i][j], 0, 0, 0);
                        acc[i][j] = __builtin_amdgcn_mfma_f32_32x32x16_bf16(ah[i], bl[j], acc[i][j], 0, 0, 0);
                        acc[i][j] = __builtin_amdgcn_mfma_f32_32x32x16_bf16(al[i], bh[j], acc[i][j], 0, 0, 0);
                    }
            }
        }
        __syncthreads();
    }

    // epilogue: C/D layout col=lane&31, row=(reg&3)+8*(reg>>2)+4*(lane>>5) (m74/m101)
#pragma unroll
    for (int i = 0; i < 2; ++i) {
#pragma unroll
        for (int j = 0; j < TN32; ++j) {
            int col = n0 + wn * (BN / 2) + j * 32 + l31;
#pragma unroll
            for (int r = 0; r < 16; ++r) {
                int row = m0 + wm * 64 + i * 32 + (r & 3) + 8 * (r >> 2) + 4 * khalf;
                C[(size_t)row * ldc + col] = acc[i][j][r];
            }
        }
    }
}

// ---------------------------------------------------------------------------
// fp32 -> 2-segment split-bf16: row = [hi (K) | lo (K)], stride 2K
// ---------------------------------------------------------------------------
__global__ __launch_bounds__(256) void split2_kernel(
    const float* __restrict__ src, unsigned short* __restrict__ dst, int K)
{
    int i = blockIdx.x * 256 + threadIdx.x;
    int m = i / K;
    int k = i - m * K;
    float a = src[i];
    __hip_bfloat16 h = __float2bfloat16(a);
    __hip_bfloat16 l = __float2bfloat16(a - __bfloat162float(h));
    unsigned short* row = dst + (size_t)m * 2 * K;
    row[k] = *(unsigned short*)&h;
    row[K + k] = *(unsigned short*)&l;
}

// ---------------------------------------------------------------------------
// x_proj split-K partial GEMM + reduce
// ---------------------------------------------------------------------------
__global__ __launch_bounds__(256) void xproj_splitk(
    const float* __restrict__ u, const float* __restrict__ Wx,
    float* __restrict__ Cp)
{
    __shared__ float As[16][68];
    __shared__ float Bs[16][100];

    const int tid = threadIdx.x;
    const int ks = blockIdx.x;
    const int m0 = blockIdx.y * 64;
    const int tx = tid & 15;
    const int ty = tid >> 4;

    float acc[4][6] = {};

    const int arow = tid >> 2;
    const int akk = (tid & 3) * 4;

    for (int k0 = ks * KC; k0 < (ks + 1) * KC; k0 += 16) {
        {
            float4 v = *(const float4*)&u[(size_t)(m0 + arow) * DINNER + k0 + akk];
            As[akk + 0][arow] = v.x;
            As[akk + 1][arow] = v.y;
            As[akk + 2][arow] = v.z;
            As[akk + 3][arow] = v.w;
        }
        for (int idx = tid; idx < 384; idx += 256) {
            int row = idx >> 2;
            int kk = (idx & 3) * 4;
            float4 v = *(const float4*)&Wx[(size_t)row * DINNER + k0 + kk];
            Bs[kk + 0][row] = v.x;
            Bs[kk + 1][row] = v.y;
            Bs[kk + 2][row] = v.z;
            Bs[kk + 3][row] = v.w;
        }
        __syncthreads();

#pragma unroll
        for (int k = 0; k < 16; ++k) {
            float a[4], b[6];
#pragma unroll
            for (int i = 0; i < 4; ++i) a[i] = As[k][ty * 4 + i];
#pragma unroll
            for (int j = 0; j < 6; ++j) b[j] = Bs[k][tx * 6 + j];
#pragma unroll
            for (int i = 0; i < 4; ++i)
#pragma unroll
                for (int j = 0; j < 6; ++j) acc[i][j] = fmaf(a[i], b[j], acc[i][j]);
        }
        __syncthreads();
    }

    float* outp = Cp + ((size_t)ks * M_ROWS + m0) * 96;
#pragma unroll
    for (int i = 0; i < 4; ++i)
#pragma unroll
        for (int j = 0; j < 6; ++j)
            outp[(ty * 4 + i) * 96 + tx * 6 + j] = acc[i][j];
}

__global__ __launch_bounds__(256) void xproj_reduce(
    const float* __restrict__ Cp, float* __restrict__ xdbl)
{
    int i = blockIdx.x * 256 + threadIdx.x;
    float s = 0.f;
#pragma unroll
    for (int c = 0; c < KSPLIT; ++c)
        s += Cp[(size_t)c * M_ROWS * 96 + i];
    xdbl[i] = s;
}

// ---------------------------------------------------------------------------
// fp32 GEMM (dt_proj, K=64)
// ---------------------------------------------------------------------------
template <int BM, int BN, int BK, int TM, int TN, bool BOUND_N, int EPI>
__global__ __launch_bounds__(256) void gemm_nt(
    const float* __restrict__ A, int lda,
    const float* __restrict__ Bmat, int ldb,
    float* __restrict__ C, int ldc,
    int M, int N, int K, const float* __restrict__ bias)
{
    __shared__ float As[BK][BM + 4];
    __shared__ float Bs[BK][BN + 4];

    const int tid = threadIdx.x;
    const int tx = tid % (BN / TN);
    const int ty = tid / (BN / TN);
    const int m0 = blockIdx.y * BM;
    const int n0 = blockIdx.x * BN;

    float acc[TM][TN];
#pragma unroll
    for (int i = 0; i < TM; ++i)
#pragma unroll
        for (int j = 0; j < TN; ++j) acc[i][j] = 0.f;

    for (int k0 = 0; k0 < K; k0 += BK) {
        for (int idx = tid * 4; idx < BM * BK; idx += 256 * 4) {
            int row = idx / BK;
            int kk = idx % BK;
            float4 v = *(const float4*)&A[(size_t)(m0 + row) * lda + k0 + kk];
            As[kk + 0][row] = v.x;
            As[kk + 1][row] = v.y;
            As[kk + 2][row] = v.z;
            As[kk + 3][row] = v.w;
        }
        for (int idx = tid * 4; idx < BN * BK; idx += 256 * 4) {
            int row = idx / BK;
            int kk = idx % BK;
            float4 v;
            if (!BOUND_N || (n0 + row) < N)
                v = *(const float4*)&Bmat[(size_t)(n0 + row) * ldb + k0 + kk];
            else
                v = make_float4(0.f, 0.f, 0.f, 0.f);
            Bs[kk + 0][row] = v.x;
            Bs[kk + 1][row] = v.y;
            Bs[kk + 2][row] = v.z;
            Bs[kk + 3][row] = v.w;
        }
        __syncthreads();

#pragma unroll
        for (int k = 0; k < BK; ++k) {
            float a[TM], b[TN];
#pragma unroll
            for (int i = 0; i < TM; ++i) a[i] = As[k][ty * TM + i];
#pragma unroll
            for (int j = 0; j < TN; ++j) b[j] = Bs[k][tx * TN + j];
#pragma unroll
            for (int i = 0; i < TM; ++i)
#pragma unroll
                for (int j = 0; j < TN; ++j) acc[i][j] = fmaf(a[i], b[j], acc[i][j]);
        }
        __syncthreads();
    }

#pragma unroll
    for (int i = 0; i < TM; ++i) {
        int m = m0 + ty * TM + i;
#pragma unroll
        for (int j = 0; j < TN; ++j) {
            int n = n0 + tx * TN + j;
            if (BOUND_N && n >= N) continue;
            float v = acc[i][j];
            if (EPI == 1) v = softplusf(v + bias[n]);
            C[(size_t)m * ldc + n] = v;
        }
    }
}

// ---------------------------------------------------------------------------
// conv + silu, float4 over channels
// ---------------------------------------------------------------------------
__global__ __launch_bounds__(256) void conv_silu_v4(
    const float* __restrict__ xz, const float* __restrict__ cw,
    const float* __restrict__ cb, float* __restrict__ u)
{
    int i = blockIdx.x * 256 + threadIdx.x;      // over M_ROWS * 512
    int dq = (i & 511) << 2;
    int bl = i >> 9;
    int b = bl >> 11;
    int l = bl & 2047;

    float4 W0 = *(const float4*)&cw[(dq + 0) * 4];
    float4 W1 = *(const float4*)&cw[(dq + 1) * 4];
    float4 W2 = *(const float4*)&cw[(dq + 2) * 4];
    float4 W3 = *(const float4*)&cw[(dq + 3) * 4];
    float4 acc = *(const float4*)&cb[dq];

#pragma unroll
    for (int k = 0; k < 4; ++k) {
        int ls = l + k - 3;
        if (ls >= 0) {
            float4 v = *(const float4*)&xz[((size_t)(b << 11) + ls) * 4096 + dq];
            acc.x = fmaf(v.x, ((const float*)&W0)[k], acc.x);
            acc.y = fmaf(v.y, ((const float*)&W1)[k], acc.y);
            acc.z = fmaf(v.z, ((const float*)&W2)[k], acc.z);
            acc.w = fmaf(v.w, ((const float*)&W3)[k], acc.w);
        }
    }
    float4 r = make_float4(siluf(acc.x), siluf(acc.y), siluf(acc.z), siluf(acc.w));
    *(float4*)&u[(size_t)bl * DINNER + dq] = r;
}

// ---------------------------------------------------------------------------
// Chunked selective scan (3 passes). PASS3 fuses gate + split-bf16 y2.
// Pass1: P = exp(Ac * sum(delta)).
// ---------------------------------------------------------------------------
template <bool PASS3>
__global__ __launch_bounds__(256) void scan_chunk(
    const float* __restrict__ dbuf, const float* __restrict__ ubuf,
    const float* __restrict__ xdbl, const float* __restrict__ A_log,
    const float* __restrict__ Dv,
    float* __restrict__ Pbuf, float* __restrict__ Sbuf,
    const float* __restrict__ xz, unsigned short* __restrict__ y2)
{
    __shared__ float sd[16][CPB];
    __shared__ float su[16][CPB];
    __shared__ float sB[16][DSTATE];
    __shared__ float sC[16][DSTATE];

    const int tid = threadIdx.x;
    const int c    = blockIdx.x % CH;
    const int dblk = (blockIdx.x / CH) % (DINNER / CPB);
    const int b    = blockIdx.x / (CH * (DINNER / CPB));
    const int d0 = dblk * CPB;
    const int dg = tid >> 2;
    const int q  = tid & 3;
    const int d  = d0 + dg;
    const size_t base_bl = (size_t)b * L_SZ + (size_t)c * CLEN;

    float Ac[4], h[4];
    float sdl = 0.f;
#pragma unroll
    for (int j = 0; j < 4; ++j)
        Ac[j] = -expf(A_log[d * DSTATE + 4 * q + j]);
    const size_t psoff = (((size_t)b * CH + c) * DINNER + d0) * DSTATE + (size_t)tid * 4;
    if (PASS3) {
        float4 h0 = *(const float4*)&Sbuf[psoff];
        h[0] = h0.x; h[1] = h0.y; h[2] = h0.z; h[3] = h0.w;
    } else {
        h[0] = h[1] = h[2] = h[3] = 0.f;
    }
    const float Dd = PASS3 ? Dv[d] : 0.f;

    const int ls = tid >> 4;
    const int g4 = (tid & 15) * 4;
    const int ln = tid & 15;

    float4 r_d = *(const float4*)&dbuf[(base_bl + ls) * DINNER + d0 + g4];
    float4 r_u = *(const float4*)&ubuf[(base_bl + ls) * DINNER + d0 + g4];
    float r_B = xdbl[(base_bl + ls) * 96 + 64 + ln];
    float r_C = xdbl[(base_bl + ls) * 96 + 80 + ln];

    for (int l0 = 0; l0 < CLEN; l0 += 16) {
        __syncthreads();
        *(float4*)&sd[ls][g4] = r_d;
        *(float4*)&su[ls][g4] = r_u;
        sB[ls][ln] = r_B;
        sC[ls][ln] = r_C;
        __syncthreads();

        if (l0 + 16 < CLEN) {
            r_d = *(const float4*)&dbuf[(base_bl + l0 + 16 + ls) * DINNER + d0 + g4];
            r_u = *(const float4*)&ubuf[(base_bl + l0 + 16 + ls) * DINNER + d0 + g4];
            r_B = xdbl[(base_bl + l0 + 16 + ls) * 96 + 64 + ln];
            r_C = xdbl[(base_bl + l0 + 16 + ls) * 96 + 80 + ln];
        }

#pragma unroll
        for (int s = 0; s < 16; ++s) {
            float dl = sd[s][dg];
            float ul = su[s][dg];
            float4 Bv = *(float4*)&sB[s][4 * q];
            float dbu = dl * ul;
            float dA0 = expf(dl * Ac[0]);
            float dA1 = expf(dl * Ac[1]);
            float dA2 = expf(dl * Ac[2]);
            float dA3 = expf(dl * Ac[3]);
            h[0] = fmaf(dA0, h[0], dbu * Bv.x);
            h[1] = fmaf(dA1, h[1], dbu * Bv.y);
            h[2] = fmaf(dA2, h[2], dbu * Bv.z);
            h[3] = fmaf(dA3, h[3], dbu * Bv.w);
            if (!PASS3) {
                sdl += dl;
            } else {
                float4 Cv = *(float4*)&sC[s][4 * q];
                float y = h[0] * Cv.x + h[1] * Cv.y + h[2] * Cv.z + h[3] * Cv.w;
                y += __shfl_xor(y, 1);
                y += __shfl_xor(y, 2);
                if (q == 0) su[s][dg] = fmaf(ul, Dd, y);
            }
        }

        if (PASS3) {
            __syncthreads();
            size_t row = base_bl + l0 + ls;
            float4 yv = *(float4*)&su[ls][g4];
            float4 rv = *(const float4*)&xz[row * 4096 + 2048 + d0 + g4];
            float a0 = yv.x * siluf(rv.x);
            float a1 = yv.y * siluf(rv.y);
            float a2 = yv.z * siluf(rv.z);
            float a3 = yv.w * siluf(rv.w);
            __hip_bfloat16 h0 = __float2bfloat16(a0), h1 = __float2bfloat16(a1);
            __hip_bfloat16 h2 = __float2bfloat16(a2), h3 = __float2bfloat16(a3);
            __hip_bfloat16 l0b = __float2bfloat16(a0 - __bfloat162float(h0));
            __hip_bfloat16 l1b = __float2bfloat16(a1 - __bfloat162float(h1));
            __hip_bfloat16 l2b = __float2bfloat16(a2 - __bfloat162float(h2));
            __hip_bfloat16 l3b = __float2bfloat16(a3 - __bfloat162float(h3));
            ushort4 hv = make_ushort4(*(unsigned short*)&h0, *(unsigned short*)&h1,
                                      *(unsigned short*)&h2, *(unsigned short*)&h3);
            ushort4 lv = make_ushort4(*(unsigned short*)&l0b, *(unsigned short*)&l1b,
                                      *(unsigned short*)&l2b, *(unsigned short*)&l3b);
            unsigned short* yrow = y2 + row * 2 * DINNER + d0 + g4;
            *(ushort4*)&yrow[0] = hv;
            *(ushort4*)&yrow[DINNER] = lv;
        }
    }

    if (!PASS3) {
        *(float4*)&Pbuf[psoff] = make_float4(expf(Ac[0] * sdl), expf(Ac[1] * sdl),
                                             expf(Ac[2] * sdl), expf(Ac[3] * sdl));
        *(float4*)&Sbuf[psoff] = make_float4(h[0], h[1], h[2], h[3]);
    }
}

__global__ __launch_bounds__(256) void scan_combine(
    const float* __restrict__ Pbuf, float* __restrict__ Sbuf)
{
    int t = blockIdx.x * 256 + threadIdx.x;
    int b = t >> 15;
    int rem = t & 32767;
    size_t base = (size_t)b * CH * DINNER * DSTATE + rem;
    float H = 0.f;
#pragma unroll 4
    for (int c = 0; c < CH; ++c) {
        size_t off = base + (size_t)c * DINNER * DSTATE;
        float S = Sbuf[off];
        float P = Pbuf[off];
        Sbuf[off] = H;
        H = fmaf(P, H, S);
    }
}

// ---------------------------------------------------------------------------
extern "C" void kernel_launch(void* const* d_in, const int* in_sizes, int n_in,
                              void* d_out, int out_size, void* d_ws, size_t ws_size,
                              hipStream_t stream)
{
    const float* x          = (const float*)d_in[0];
    const float* in_proj_w  = (const float*)d_in[1];
    const float* conv_w     = (const float*)d_in[2];
    const float* conv_b     = (const float*)d_in[3];
    const float* x_proj_w   = (const float*)d_in[4];
    const float* dt_proj_w  = (const float*)d_in[5];
    const float* dt_proj_b  = (const float*)d_in[6];
    const float* A_log      = (const float*)d_in[7];
    const float* Dv         = (const float*)d_in[8];
    const float* out_proj_w = (const float*)d_in[9];
    float* out = (float*)d_out;

    // workspace layout (bytes):
    char* w = (char*)d_ws;
    float* xz   = (float*)(w);                       // 64 MB
    float* u    = (float*)(w + 67108864);            // 32 MB
    float* dbuf = (float*)(w + 100663296);           // 32 MB
    float* xdbl = (float*)(w + 134217728);           // 1.5 MB
    float* Pbuf = (float*)(w + 135790592);           // 8 MB
    float* Sbuf = (float*)(w + 144179200);           // 8 MB (ends 152567808)
    unsigned short* x2  = (unsigned short*)(w + 152567808);  // 16 MB [4096][2048]
    unsigned short* w2a = (unsigned short*)(w + 169345024);  // 16 MB [4096][2048]
    unsigned short* y2  = x2;                                 // 32 MB [4096][4096] (stage 6+)
    unsigned short* w2b = (unsigned short*)(w + 135790592);   // 8 MB [1024][4096] over Pbuf (dead)
    float* Cp = (float*)(w + 152567808);             // xproj partials (x2 region, dead at 4)

    // 1) split x and in_proj_w to 2-segment bf16
    split2_kernel<<<(M_ROWS * DMODEL) / 256, 256, 0, stream>>>(x, x2, DMODEL);
    split2_kernel<<<(2 * DINNER * DMODEL) / 256, 256, 0, stream>>>(in_proj_w, w2a, DMODEL);
    // 2) in_proj via 32x32x16 MFMA (single-pass segment fusion)
    {
        dim3 g(4096 / 128, M_ROWS / 128);
        gemm_bf16_nt<128, 1024><<<g, 256, 0, stream>>>(x2, w2a, xz, 4096);
    }
    // 3) conv + silu -> u
    conv_silu_v4<<<(M_ROWS * 512) / 256, 256, 0, stream>>>(xz, conv_w, conv_b, u);
    // 4) x_proj via split-K
    {
        dim3 g(KSPLIT, M_ROWS / 64);
        xproj_splitk<<<g, 256, 0, stream>>>(u, x_proj_w, Cp);
        xproj_reduce<<<(M_ROWS * 96) / 256, 256, 0, stream>>>(Cp, xdbl);
    }
    // 5) dt_proj + softplus -> dbuf (fp32, K=64)
    {
        dim3 g(2048 / 128, M_ROWS / 128);
        gemm_nt<128, 128, 16, 8, 8, false, 1><<<g, 256, 0, stream>>>(
            xdbl, 96, dt_proj_w, 64, dbuf, 2048, M_ROWS, 2048, 64, dt_proj_b);
    }
    // 6) chunked selective scan; pass3 fuses gate + split into y2
    {
        const int nblk = B_SZ * (DINNER / CPB) * CH;
        scan_chunk<false><<<nblk, 256, 0, stream>>>(dbuf, u, xdbl, A_log, Dv, Pbuf, Sbuf, nullptr, nullptr);
        scan_combine<<<B_SZ * DINNER * DSTATE / 256, 256, 0, stream>>>(Pbuf, Sbuf);
        scan_chunk<true><<<nblk, 256, 0, stream>>>(dbuf, u, xdbl, A_log, Dv, nullptr, Sbuf, xz, y2);
    }
    // 7) split out_proj_w
    split2_kernel<<<(DMODEL * DINNER) / 256, 256, 0, stream>>>(out_proj_w, w2b, DINNER);
    // 8) out_proj via 32x32x16 MFMA (single-pass segment fusion)
    {
        dim3 g(1024 / 64, M_ROWS / 128);
        gemm_bf16_nt<64, 2048><<<g, 256, 0, stream>>>(y2, w2b, out, 1024);
    }
}